// Round 11
// baseline (131.036 us; speedup 1.0000x reference)
//
#include <hip/hip_runtime.h>
#include <hip/hip_bf16.h>

#define D 128
#define H 256
#define NB 32
#define NN 128

typedef __attribute__((ext_vector_type(8))) short short8;
typedef __attribute__((ext_vector_type(4))) float f32x4;
typedef __attribute__((ext_vector_type(2))) float f32x2;
typedef __attribute__((ext_vector_type(4))) unsigned int uint4v;

__device__ __forceinline__ unsigned short to_bf16u(float f) {
  unsigned u = __builtin_bit_cast(unsigned, f);
  u = (u + 0x7fffu + ((u >> 16) & 1u)) >> 16;
  return (unsigned short)u;
}

// packed f32x2 -> bf16x2 (RNE); v_cvt_pk_bf16_f32
__device__ __forceinline__ unsigned cvt_pk(float lo, float hi) {
  union { __hip_bfloat162_raw h; unsigned u; } c;
  __hip_bfloat162 t = __float22bfloat162_rn(make_float2(lo, hi));
  c.h = *reinterpret_cast<__hip_bfloat162_raw*>(&t);
  return c.u;
}

// v_pk_add_f32: two f32 adds in one VOP3P instruction (verified R7/R8/R9)
__device__ __forceinline__ f32x2 pk_add(f32x2 a, f32x2 b) {
  f32x2 d;
  asm("v_pk_add_f32 %0, %1, %2" : "=v"(d) : "v"(a), "v"(b));
  return d;
}

// packed relu on bf16 pair: signed-i16 max with 0 == relu (verified R7/R8/R9)
// NOTE: v_pk_add_bf16 does NOT exist on gfx950 (R10 compile fail).
__device__ __forceinline__ unsigned pk_relu(unsigned x) {
  unsigned d;
  asm("v_pk_max_i16 %0, %1, %2" : "=v"(d) : "v"(x), "v"(0u));
  return d;
}

// ---------------- Kernel 1: LN*mask + mw1 projections; blocks >=512 repack mw2 ----
__global__ __launch_bounds__(512) void k_ln_proj(
    const float* __restrict__ nodes, const float* __restrict__ node_mask,
    const float* __restrict__ ln_g, const float* __restrict__ ln_b,
    const float* __restrict__ mw1, const float* __restrict__ mw2,
    float* __restrict__ xi_p, unsigned short* __restrict__ xjb,
    short* __restrict__ bw2) {
  const int tid = threadIdx.x;
  if (blockIdx.x >= 512) {
    // repack mw2 [H][D] f32 -> bf16 MFMA B-fragment order.
    const int t = (blockIdx.x - 512) * 512 + tid;  // 0..4095
    const int lane = t & 63;
    const int tile = t >> 6;
    const int ks = tile >> 3, nt = tile & 7;
#pragma unroll
    for (int e = 0; e < 8; ++e) {
      int k = ks * 32 + ((lane >> 4) << 3) + e;
      int d = nt * 16 + (lane & 15);
      bw2[(size_t)t * 8 + e] = (short)to_bf16u(mw2[k * D + d]);
    }
    return;
  }
  const int row0 = blockIdx.x * 8;
  __shared__ float xs[8][128];
  __shared__ float part[2][8][256];   // team-1 partials (ai, aj)

  {
    const int r = tid >> 6;           // 0..7, wave = row
    const int c2 = (tid & 63) << 1;
    float2 v = *(const float2*)(nodes + (size_t)(row0 + r) * D + c2);
    float s1 = v.x + v.y;
    float s2 = v.x * v.x + v.y * v.y;
#pragma unroll
    for (int off = 1; off < 64; off <<= 1) {
      s1 += __shfl_xor(s1, off);
      s2 += __shfl_xor(s2, off);
    }
    float mu = s1 * (1.0f / 128.0f);
    float var = s2 * (1.0f / 128.0f) - mu * mu;
    float rsig = rsqrtf(var + 1e-5f);
    float m = node_mask[row0 + r];
    float2 g2 = *(const float2*)(ln_g + c2);
    float2 b2 = *(const float2*)(ln_b + c2);
    xs[r][c2]     = ((v.x - mu) * rsig * g2.x + b2.x) * m;
    xs[r][c2 + 1] = ((v.y - mu) * rsig * g2.y + b2.y) * m;
  }
  __syncthreads();

  const int col = tid & 255, team = tid >> 8, d0 = team * 64;
  float ai[8], aj[8];
#pragma unroll
  for (int rr = 0; rr < 8; ++rr) { ai[rr] = 0.f; aj[rr] = 0.f; }
#pragma unroll 4
  for (int d = d0; d < d0 + 64; ++d) {
    float wi = mw1[d * H + col];
    float wj = mw1[(D + d) * H + col];
#pragma unroll
    for (int rr = 0; rr < 8; ++rr) {
      float xv = xs[rr][d];
      ai[rr] = fmaf(xv, wi, ai[rr]);
      aj[rr] = fmaf(xv, wj, aj[rr]);
    }
  }
  if (team == 1) {
#pragma unroll
    for (int rr = 0; rr < 8; ++rr) {
      part[0][rr][col] = ai[rr];
      part[1][rr][col] = aj[rr];
    }
  }
  __syncthreads();
  if (team == 0) {
#pragma unroll
    for (int rr = 0; rr < 8; ++rr) {
      float a = ai[rr] + part[0][rr][col];
      float c = aj[rr] + part[1][rr][col];
      xi_p[(size_t)(row0 + rr) * H + col] = a;
      xjb[(size_t)(row0 + rr) * H + col] = to_bf16u(c);
    }
  }
}

// ---------------- Kernel 2: msgs GEMM + mask + sum over j -> agg ----------------
// TM=64/NT=64 (R9's verified-correct mapping/epilogue). Changes vs R9:
//  - FULL unroll on ks (R9's unroll-1 serialized loads: 83us; R7's full unroll
//    at 128-reg cap spilled: 74MB writes)
//  - __launch_bounds__(512,3): cap ~170 VGPR fits the ~140 live set, and R8's
//    measured occupancy was ~12 waves/CU anyway, so nothing real is lost.
// Held bf[4]: each B ds_read_b128 feeds 4 MFMAs -> per-i LDS B-traffic halves
// vs R8 (the 25.6us dominant pipe).
__global__ __launch_bounds__(512, 3) void k_msgs(
    const float* __restrict__ xi_p, const unsigned short* __restrict__ xjb,
    const short* __restrict__ bw2g, const float* __restrict__ mb1,
    const float* __restrict__ mb2, const float* __restrict__ node_mask,
    float* __restrict__ agg) {
  const int b = blockIdx.y;
  const int i0 = blockIdx.x * 2;
  const int tid = threadIdx.x;           // 0..511
  const int w = tid >> 6, l = tid & 63;  // 8 waves
  const int iw = w >> 2;                 // 0..1: which i
  const int jslab = (w >> 1) & 1;        // 0..1: which 64-row j-slab
  const int nh = w & 1;                  // 0..1: which 64-col half
  const int jbase = jslab * 64;
  const int lg = l >> 4, l15 = l & 15;

  __shared__ short bw2s[32768];          // 64 KB B fragments
  __shared__ float cs[2][256];           // xi_p row + mb1 (f32), per i
  __shared__ float mb2s[128], maskS[128];
  __shared__ float waveAgg[8][64];

  {
    const uint4v* src = (const uint4v*)bw2g;
    uint4v* dst = (uint4v*)bw2s;
#pragma unroll
    for (int c = 0; c < 8; ++c) dst[c * 512 + tid] = src[c * 512 + tid];
  }
  {
    int ii = tid >> 8, k = tid & 255;    // 512 threads = 2 x 256
    cs[ii][k] = xi_p[(size_t)(b * NN + i0 + ii) * H + k] + mb1[k];
  }
  if (tid < 128) { mb2s[tid] = mb2[tid]; maskS[tid] = node_mask[b * NN + tid]; }
  __syncthreads();

  const unsigned short* xbase = xjb + (size_t)(b * NN + jbase + l15) * H;

  f32x4 acc[4][4];
#pragma unroll
  for (int mf = 0; mf < 4; ++mf)
#pragma unroll
    for (int nt = 0; nt < 4; ++nt)
      acc[mf][nt] = (f32x4){0.f, 0.f, 0.f, 0.f};

  const short8* bfrag = (const short8*)bw2s;

#pragma unroll
  for (int ks = 0; ks < 8; ++ks) {
    const int kb = ks * 32 + lg * 8;     // bf16-elem k offset
    short8 bf[4];                        // held across mf: 1 read / 4 MFMAs
#pragma unroll
    for (int nt = 0; nt < 4; ++nt)
      bf[nt] = bfrag[(ks * 8 + nh * 4 + nt) * 64 + l];
    f32x2 cc[4];
    {
      f32x4 c0 = *(const f32x4*)(&cs[iw][kb]);
      f32x4 c1 = *(const f32x4*)(&cs[iw][kb + 4]);
      cc[0] = (f32x2){c0.x, c0.y}; cc[1] = (f32x2){c0.z, c0.w};
      cc[2] = (f32x2){c1.x, c1.y}; cc[3] = (f32x2){c1.z, c1.w};
    }
#pragma unroll
    for (int mf = 0; mf < 4; ++mf) {
      uint4v xu = *(const uint4v*)(xbase + mf * 16 * H + kb);
      uint4v au;
#pragma unroll
      for (int p = 0; p < 4; ++p) {
        f32x2 xf;
        xf[0] = __builtin_bit_cast(float, xu[p] << 16);
        xf[1] = __builtin_bit_cast(float, xu[p] & 0xffff0000u);
        f32x2 s = pk_add(xf, cc[p]);
        au[p] = pk_relu(cvt_pk(s[0], s[1]));
      }
      short8 af = __builtin_bit_cast(short8, au);
#pragma unroll
      for (int nt = 0; nt < 4; ++nt)
        acc[mf][nt] = __builtin_amdgcn_mfma_f32_16x16x32_bf16(af, bf[nt], acc[mf][nt], 0, 0, 0);
    }
  }

  // Epilogue: relu(acc+mb2)*mask_j, column-sum over the wave's 64 rows.
#pragma unroll
  for (int nt = 0; nt < 4; ++nt) {
    const float bias = mb2s[nh * 64 + nt * 16 + l15];
    float s = 0.f;
#pragma unroll
    for (int mf = 0; mf < 4; ++mf) {
      const int jb = jbase + mf * 16 + lg * 4;
#pragma unroll
      for (int r = 0; r < 4; ++r)
        s = fmaf(fmaxf(acc[mf][nt][r] + bias, 0.f), maskS[jb + r], s);
    }
    s += __shfl_xor(s, 16);
    s += __shfl_xor(s, 32);
    if (l < 16) waveAgg[w][nt * 16 + l15] = s;
  }
  __syncthreads();
  if (tid < 256) {
    const int ii = tid >> 7, col = tid & 127;  // 2 i's x 128 cols
    const int nh2 = col >> 6, c6 = col & 63;
    agg[(size_t)(b * NN + i0 + ii) * D + col] =
        waveAgg[ii * 4 + nh2][c6] + waveAgg[ii * 4 + 2 + nh2][c6];
  }
}

// ---------------- Kernel 3: update MLP + residual + mask ----------------
__global__ __launch_bounds__(512) void k_upd(
    const float* __restrict__ nodes, const float* __restrict__ agg,
    const float* __restrict__ uw1, const float* __restrict__ ub1,
    const float* __restrict__ uw2, const float* __restrict__ ub2,
    const float* __restrict__ node_mask, float* __restrict__ out) {
  const int row0 = blockIdx.x * 8;
  const int tid = threadIdx.x;
  __shared__ float ns[8][128];
  __shared__ float as2[8][128];
  __shared__ float us[8][256];
  __shared__ float pus[8][256];
  {
    const int r = tid >> 6;
    const int c2 = (tid & 63) << 1;
    *(float2*)(&ns[r][c2]) = *(const float2*)(nodes + (size_t)(row0 + r) * D + c2);
    *(float2*)(&as2[r][c2]) = *(const float2*)(agg + (size_t)(row0 + r) * D + c2);
  }
  __syncthreads();

  const int col = tid & 255, team = tid >> 8, d0 = team * 64;
  float acc8[8];
#pragma unroll
  for (int rr = 0; rr < 8; ++rr) acc8[rr] = 0.f;
#pragma unroll 4
  for (int d = d0; d < d0 + 64; ++d) {
    float wa = uw1[d * H + col];
    float wb = uw1[(D + d) * H + col];
#pragma unroll
    for (int rr = 0; rr < 8; ++rr) {
      acc8[rr] = fmaf(ns[rr][d], wa, acc8[rr]);
      acc8[rr] = fmaf(as2[rr][d], wb, acc8[rr]);
    }
  }
  if (team == 1) {
#pragma unroll
    for (int rr = 0; rr < 8; ++rr) pus[rr][col] = acc8[rr];
  }
  __syncthreads();
  if (team == 0) {
    float bias = ub1[col];
#pragma unroll
    for (int rr = 0; rr < 8; ++rr)
      us[rr][col] = fmaxf(acc8[rr] + pus[rr][col] + bias, 0.f);
  }
  __syncthreads();

  const int colD = tid & 127, rg = tid >> 7;  // rows rg and rg+4
  float o0 = 0.f, o1 = 0.f;
#pragma unroll 8
  for (int h = 0; h < 256; ++h) {
    float wv = uw2[h * D + colD];
    o0 = fmaf(us[rg][h], wv, o0);
    o1 = fmaf(us[rg + 4][h], wv, o1);
  }
  const float ub2v = ub2[colD];
  out[(size_t)(row0 + rg) * D + colD] =
      (ns[rg][colD] + o0 + ub2v) * node_mask[row0 + rg];
  out[(size_t)(row0 + rg + 4) * D + colD] =
      (ns[rg + 4][colD] + o1 + ub2v) * node_mask[row0 + rg + 4];
}

extern "C" void kernel_launch(void* const* d_in, const int* in_sizes, int n_in,
                              void* d_out, int out_size, void* d_ws, size_t ws_size,
                              hipStream_t stream) {
  (void)in_sizes; (void)n_in; (void)out_size; (void)ws_size;
  const float* nodes     = (const float*)d_in[0];
  const float* node_mask = (const float*)d_in[1];
  const float* ln_g      = (const float*)d_in[2];
  const float* ln_b      = (const float*)d_in[3];
  const float* mw1       = (const float*)d_in[4];
  const float* mb1       = (const float*)d_in[5];
  const float* mw2       = (const float*)d_in[6];
  const float* mb2       = (const float*)d_in[7];
  const float* uw1       = (const float*)d_in[8];
  const float* ub1       = (const float*)d_in[9];
  const float* uw2       = (const float*)d_in[10];
  const float* ub2       = (const float*)d_in[11];
  float* out = (float*)d_out;

  char* ws = (char*)d_ws;
  float*          xi_p = (float*)(ws);                              // 4 MB
  unsigned short* xjb  = (unsigned short*)(ws + ((size_t)4 << 20)); // 2 MB
  float*          agg  = (float*)(ws + ((size_t)6 << 20));          // 2 MB
  short*          bw2  = (short*)(ws + ((size_t)8 << 20));          // 64 KB

  k_ln_proj<<<520, 512, 0, stream>>>(nodes, node_mask, ln_g, ln_b, mw1, mw2,
                                     xi_p, xjb, bw2);
  k_msgs<<<dim3(NN / 2, NB), 512, 0, stream>>>(xi_p, xjb, bw2, mb1, mb2, node_mask, agg);
  k_upd<<<512, 512, 0, stream>>>(nodes, agg, uw1, ub1, uw2, ub2, node_mask, out);
}

// Round 12
// 112.562 us; speedup vs baseline: 1.1641x; 1.1641x over previous
//
#include <hip/hip_runtime.h>
#include <hip/hip_bf16.h>

#define D 128
#define H 256
#define NB 32
#define NN 128

typedef __attribute__((ext_vector_type(8))) short short8;
typedef __attribute__((ext_vector_type(4))) float f32x4;
typedef __attribute__((ext_vector_type(2))) float f32x2;
typedef __attribute__((ext_vector_type(4))) unsigned int uint4v;

__device__ __forceinline__ unsigned short to_bf16u(float f) {
  unsigned u = __builtin_bit_cast(unsigned, f);
  u = (u + 0x7fffu + ((u >> 16) & 1u)) >> 16;
  return (unsigned short)u;
}

// packed f32x2 -> bf16x2 (RNE); v_cvt_pk_bf16_f32
__device__ __forceinline__ unsigned cvt_pk(float lo, float hi) {
  union { __hip_bfloat162_raw h; unsigned u; } c;
  __hip_bfloat162 t = __float22bfloat162_rn(make_float2(lo, hi));
  c.h = *reinterpret_cast<__hip_bfloat162_raw*>(&t);
  return c.u;
}

// v_pk_add_f32 (verified R7-R9). v_pk_add_bf16 does NOT exist on gfx950 (R10).
__device__ __forceinline__ f32x2 pk_add(f32x2 a, f32x2 b) {
  f32x2 d;
  asm("v_pk_add_f32 %0, %1, %2" : "=v"(d) : "v"(a), "v"(b));
  return d;
}

// packed relu on bf16 pair: signed-i16 max with 0 (verified R7-R9)
__device__ __forceinline__ unsigned pk_relu(unsigned x) {
  unsigned d;
  asm("v_pk_max_i16 %0, %1, %2" : "=v"(d) : "v"(x), "v"(0u));
  return d;
}

// ---------------- Kernel 1: LN*mask + mw1 projections (16 rows/block);
// ---------------- blocks >= 256 repack mw2 into MFMA B-fragment order.
__global__ __launch_bounds__(512) void k_ln_proj(
    const float* __restrict__ nodes, const float* __restrict__ node_mask,
    const float* __restrict__ ln_g, const float* __restrict__ ln_b,
    const float* __restrict__ mw1, const float* __restrict__ mw2,
    float* __restrict__ xi_p, unsigned short* __restrict__ xjb,
    short* __restrict__ bw2) {
  const int tid = threadIdx.x;
  if (blockIdx.x >= 256) {
    const int t = (blockIdx.x - 256) * 512 + tid;  // 0..4095
    const int lane = t & 63;
    const int tile = t >> 6;
    const int ks = tile >> 3, nt = tile & 7;
#pragma unroll
    for (int e = 0; e < 8; ++e) {
      int k = ks * 32 + ((lane >> 4) << 3) + e;
      int d = nt * 16 + (lane & 15);
      bw2[(size_t)t * 8 + e] = (short)to_bf16u(mw2[k * D + d]);
    }
    return;
  }
  const int row0 = blockIdx.x * 16;
  __shared__ float xs[16][128];
  __shared__ float part[2][16][256];   // team-1 partials (ai, aj): 64 KB

  {
    const int r = tid >> 5;            // 0..15, 32 lanes per row
    const int c4 = (tid & 31) << 2;
    float4 v = *(const float4*)(nodes + (size_t)(row0 + r) * D + c4);
    float s1 = v.x + v.y + v.z + v.w;
    float s2 = v.x * v.x + v.y * v.y + v.z * v.z + v.w * v.w;
#pragma unroll
    for (int off = 1; off < 32; off <<= 1) {
      s1 += __shfl_xor(s1, off);
      s2 += __shfl_xor(s2, off);
    }
    float mu = s1 * (1.0f / 128.0f);
    float var = s2 * (1.0f / 128.0f) - mu * mu;
    float rsig = rsqrtf(var + 1e-5f);
    float m = node_mask[row0 + r];
    float4 g4 = *(const float4*)(ln_g + c4);
    float4 b4 = *(const float4*)(ln_b + c4);
    xs[r][c4]     = ((v.x - mu) * rsig * g4.x + b4.x) * m;
    xs[r][c4 + 1] = ((v.y - mu) * rsig * g4.y + b4.y) * m;
    xs[r][c4 + 2] = ((v.z - mu) * rsig * g4.z + b4.z) * m;
    xs[r][c4 + 3] = ((v.w - mu) * rsig * g4.w + b4.w) * m;
  }
  __syncthreads();

  const int col = tid & 255, team = tid >> 8, d0 = team * 64;
  float ai[16], aj[16];
#pragma unroll
  for (int rr = 0; rr < 16; ++rr) { ai[rr] = 0.f; aj[rr] = 0.f; }
#pragma unroll 4
  for (int d = d0; d < d0 + 64; ++d) {
    float wi = mw1[d * H + col];
    float wj = mw1[(D + d) * H + col];
#pragma unroll
    for (int rr = 0; rr < 16; ++rr) {
      float xv = xs[rr][d];
      ai[rr] = fmaf(xv, wi, ai[rr]);
      aj[rr] = fmaf(xv, wj, aj[rr]);
    }
  }
  if (team == 1) {
#pragma unroll
    for (int rr = 0; rr < 16; ++rr) {
      part[0][rr][col] = ai[rr];
      part[1][rr][col] = aj[rr];
    }
  }
  __syncthreads();
  if (team == 0) {
#pragma unroll
    for (int rr = 0; rr < 16; ++rr) {
      float a = ai[rr] + part[0][rr][col];
      float c = aj[rr] + part[1][rr][col];
      xi_p[(size_t)(row0 + rr) * H + col] = a;
      xjb[(size_t)(row0 + rr) * H + col] = to_bf16u(c);
    }
  }
}

// ---------------- Kernel 2: msgs GEMM + mask + sum over j -> agg ----------------
// R8-proven tile (TM=32, NT=128, mf=2, acc[2][8]=64 AGPR, full unroll) with ONE
// change: B-fragments read DIRECTLY FROM GLOBAL (bw2 is 64KB, L2-resident;
// total B traffic 16.8MB ~ 0.5us of L2 BW). Removes the dominant per-CU LDS
// pipe (~20us of ds_read_b128), the 64KB staging + barrier; block LDS ~7KB.
// Spill tripwire: WRITE_SIZE must stay ~2MB.
__global__ __launch_bounds__(512, 4) void k_msgs(
    const float* __restrict__ xi_p, const unsigned short* __restrict__ xjb,
    const short* __restrict__ bw2g, const float* __restrict__ mb1,
    const float* __restrict__ mb2, const float* __restrict__ node_mask,
    float* __restrict__ agg) {
  const int b = blockIdx.y;
  const int i0 = blockIdx.x * 2;
  const int tid = threadIdx.x;           // 0..511
  const int w = tid >> 6, l = tid & 63;  // 8 waves
  const int iw = w >> 2;                 // 0..1: which i
  const int jbase = (w & 3) * 32;        // which 32-row j-slab
  const int lg = l >> 4, l15 = l & 15;

  __shared__ float cs[2][256];           // xi_p row + mb1 (f32), per i
  __shared__ float mb2s[128], maskS[128];
  __shared__ float waveAgg[8][128];

  {
    int ii = tid >> 8, k = tid & 255;    // 512 threads = 2 x 256
    cs[ii][k] = xi_p[(size_t)(b * NN + i0 + ii) * H + k] + mb1[k];
  }
  if (tid < 128) { mb2s[tid] = mb2[tid]; maskS[tid] = node_mask[b * NN + tid]; }
  __syncthreads();

  const unsigned short* xrow[2];
#pragma unroll
  for (int mf = 0; mf < 2; ++mf)
    xrow[mf] = xjb + (size_t)(b * NN + jbase + mf * 16 + l15) * H;

  f32x4 acc[2][8];
#pragma unroll
  for (int mf = 0; mf < 2; ++mf)
#pragma unroll
    for (int nt = 0; nt < 8; ++nt)
      acc[mf][nt] = (f32x4){0.f, 0.f, 0.f, 0.f};

  const short8* bfrag = (const short8*)bw2g;   // global, L2-resident

#pragma unroll
  for (int ks = 0; ks < 8; ++ks) {
    const int kb = ks * 32 + lg * 8;     // bf16-elem k offset
    f32x2 cc[4];
    {
      f32x4 c0 = *(const f32x4*)(&cs[iw][kb]);
      f32x4 c1 = *(const f32x4*)(&cs[iw][kb + 4]);
      cc[0] = (f32x2){c0.x, c0.y}; cc[1] = (f32x2){c0.z, c0.w};
      cc[2] = (f32x2){c1.x, c1.y}; cc[3] = (f32x2){c1.z, c1.w};
    }
    short8 af[2];
#pragma unroll
    for (int mf = 0; mf < 2; ++mf) {
      uint4v xu = *(const uint4v*)(xrow[mf] + kb);
      uint4v au;
#pragma unroll
      for (int p = 0; p < 4; ++p) {
        f32x2 xf;
        xf[0] = __builtin_bit_cast(float, xu[p] << 16);
        xf[1] = __builtin_bit_cast(float, xu[p] & 0xffff0000u);
        f32x2 s = pk_add(xf, cc[p]);
        au[p] = pk_relu(cvt_pk(s[0], s[1]));
      }
      af[mf] = __builtin_bit_cast(short8, au);
    }
#pragma unroll
    for (int nt = 0; nt < 8; ++nt) {
      short8 bf = bfrag[(ks * 8 + nt) * 64 + l];
#pragma unroll
      for (int mf = 0; mf < 2; ++mf)
        acc[mf][nt] = __builtin_amdgcn_mfma_f32_16x16x32_bf16(af[mf], bf, acc[mf][nt], 0, 0, 0);
    }
  }

  // Epilogue: relu(acc+mb2)*mask_j, column-sum over the wave's 32 rows.
#pragma unroll
  for (int nt = 0; nt < 8; ++nt) {
    const float bias = mb2s[nt * 16 + l15];
    float s = 0.f;
#pragma unroll
    for (int mf = 0; mf < 2; ++mf) {
      const int jb = jbase + mf * 16 + lg * 4;
#pragma unroll
      for (int r = 0; r < 4; ++r)
        s = fmaf(fmaxf(acc[mf][nt][r] + bias, 0.f), maskS[jb + r], s);
    }
    s += __shfl_xor(s, 16);
    s += __shfl_xor(s, 32);
    if (l < 16) waveAgg[w][nt * 16 + l15] = s;
  }
  __syncthreads();
  if (tid < 256) {
    const int ii = tid >> 7, col = tid & 127;  // 2 i's x 128 cols
    agg[(size_t)(b * NN + i0 + ii) * D + col] =
        waveAgg[ii * 4][col] + waveAgg[ii * 4 + 1][col] +
        waveAgg[ii * 4 + 2][col] + waveAgg[ii * 4 + 3][col];
  }
}

// ---------------- Kernel 3: update MLP + residual + mask (16 rows/block) --------
__global__ __launch_bounds__(512) void k_upd(
    const float* __restrict__ nodes, const float* __restrict__ agg,
    const float* __restrict__ uw1, const float* __restrict__ ub1,
    const float* __restrict__ uw2, const float* __restrict__ ub2,
    const float* __restrict__ node_mask, float* __restrict__ out) {
  const int row0 = blockIdx.x * 16;
  const int tid = threadIdx.x;
  __shared__ float ns[16][128];
  __shared__ float as2[16][128];
  __shared__ float us[16][256];
  __shared__ float pus[16][256];
  {
    const int r = tid >> 5;            // 0..15
    const int c4 = (tid & 31) << 2;
    *(float4*)(&ns[r][c4]) = *(const float4*)(nodes + (size_t)(row0 + r) * D + c4);
    *(float4*)(&as2[r][c4]) = *(const float4*)(agg + (size_t)(row0 + r) * D + c4);
  }
  __syncthreads();

  const int col = tid & 255, team = tid >> 8, d0 = team * 64;
  float acc16[16];
#pragma unroll
  for (int rr = 0; rr < 16; ++rr) acc16[rr] = 0.f;
#pragma unroll 4
  for (int d = d0; d < d0 + 64; ++d) {
    float wa = uw1[d * H + col];
    float wb = uw1[(D + d) * H + col];
#pragma unroll
    for (int rr = 0; rr < 16; ++rr) {
      acc16[rr] = fmaf(ns[rr][d], wa, acc16[rr]);
      acc16[rr] = fmaf(as2[rr][d], wb, acc16[rr]);
    }
  }
  if (team == 1) {
#pragma unroll
    for (int rr = 0; rr < 16; ++rr) pus[rr][col] = acc16[rr];
  }
  __syncthreads();
  if (team == 0) {
    float bias = ub1[col];
#pragma unroll
    for (int rr = 0; rr < 16; ++rr)
      us[rr][col] = fmaxf(acc16[rr] + pus[rr][col] + bias, 0.f);
  }
  __syncthreads();

  const int colD = tid & 127, rg = tid >> 7;  // rg 0..3; rows rg+4p
  float o[4] = {0.f, 0.f, 0.f, 0.f};
#pragma unroll 8
  for (int h = 0; h < 256; ++h) {
    float wv = uw2[h * D + colD];
#pragma unroll
    for (int p = 0; p < 4; ++p) o[p] = fmaf(us[rg + 4 * p][h], wv, o[p]);
  }
  const float ub2v = ub2[colD];
#pragma unroll
  for (int p = 0; p < 4; ++p) {
    const int rr = rg + 4 * p;
    out[(size_t)(row0 + rr) * D + colD] =
        (ns[rr][colD] + o[p] + ub2v) * node_mask[row0 + rr];
  }
}

extern "C" void kernel_launch(void* const* d_in, const int* in_sizes, int n_in,
                              void* d_out, int out_size, void* d_ws, size_t ws_size,
                              hipStream_t stream) {
  (void)in_sizes; (void)n_in; (void)out_size; (void)ws_size;
  const float* nodes     = (const float*)d_in[0];
  const float* node_mask = (const float*)d_in[1];
  const float* ln_g      = (const float*)d_in[2];
  const float* ln_b      = (const float*)d_in[3];
  const float* mw1       = (const float*)d_in[4];
  const float* mb1       = (const float*)d_in[5];
  const float* mw2       = (const float*)d_in[6];
  const float* mb2       = (const float*)d_in[7];
  const float* uw1       = (const float*)d_in[8];
  const float* ub1       = (const float*)d_in[9];
  const float* uw2       = (const float*)d_in[10];
  const float* ub2       = (const float*)d_in[11];
  float* out = (float*)d_out;

  char* ws = (char*)d_ws;
  float*          xi_p = (float*)(ws);                              // 4 MB
  unsigned short* xjb  = (unsigned short*)(ws + ((size_t)4 << 20)); // 2 MB
  float*          agg  = (float*)(ws + ((size_t)6 << 20));          // 2 MB
  short*          bw2  = (short*)(ws + ((size_t)8 << 20));          // 64 KB

  k_ln_proj<<<264, 512, 0, stream>>>(nodes, node_mask, ln_g, ln_b, mw1, mw2,
                                     xi_p, xjb, bw2);
  k_msgs<<<dim3(NN / 2, NB), 512, 0, stream>>>(xi_p, xjb, bw2, mb1, mb2, node_mask, agg);
  k_upd<<<256, 512, 0, stream>>>(nodes, agg, uw1, ub1, uw2, ub2, node_mask, out);
}

// Round 13
// 84.301 us; speedup vs baseline: 1.5544x; 1.3352x over previous
//
#include <hip/hip_runtime.h>
#include <hip/hip_bf16.h>

#define D 128
#define H 256
#define NB 32
#define NN 128

typedef __attribute__((ext_vector_type(8))) short short8;
typedef __attribute__((ext_vector_type(4))) float f32x4;
typedef __attribute__((ext_vector_type(2))) float f32x2;
typedef __attribute__((ext_vector_type(4))) unsigned int uint4v;

__device__ __forceinline__ unsigned short to_bf16u(float f) {
  unsigned u = __builtin_bit_cast(unsigned, f);
  u = (u + 0x7fffu + ((u >> 16) & 1u)) >> 16;
  return (unsigned short)u;
}

// packed f32x2 -> bf16x2 (RNE); v_cvt_pk_bf16_f32
__device__ __forceinline__ unsigned cvt_pk(float lo, float hi) {
  union { __hip_bfloat162_raw h; unsigned u; } c;
  __hip_bfloat162 t = __float22bfloat162_rn(make_float2(lo, hi));
  c.h = *reinterpret_cast<__hip_bfloat162_raw*>(&t);
  return c.u;
}

// v_pk_add_f32 (verified R7-R9). v_pk_add_bf16 does NOT exist on gfx950 (R10).
__device__ __forceinline__ f32x2 pk_add(f32x2 a, f32x2 b) {
  f32x2 d;
  asm("v_pk_add_f32 %0, %1, %2" : "=v"(d) : "v"(a), "v"(b));
  return d;
}

// packed relu on bf16 pair: signed-i16 max with 0 (verified R7-R9)
__device__ __forceinline__ unsigned pk_relu(unsigned x) {
  unsigned d;
  asm("v_pk_max_i16 %0, %1, %2" : "=v"(d) : "v"(x), "v"(0u));
  return d;
}

// ---------------- Kernel 1: LN*mask + mw1 projections; blocks >=512 repack mw2 ----
__global__ __launch_bounds__(512) void k_ln_proj(
    const float* __restrict__ nodes, const float* __restrict__ node_mask,
    const float* __restrict__ ln_g, const float* __restrict__ ln_b,
    const float* __restrict__ mw1, const float* __restrict__ mw2,
    float* __restrict__ xi_p, unsigned short* __restrict__ xjb,
    short* __restrict__ bw2) {
  const int tid = threadIdx.x;
  if (blockIdx.x >= 512) {
    // repack mw2 [H][D] f32 -> bf16 MFMA B-fragment order.
    const int t = (blockIdx.x - 512) * 512 + tid;  // 0..4095
    const int lane = t & 63;
    const int tile = t >> 6;
    const int ks = tile >> 3, nt = tile & 7;
#pragma unroll
    for (int e = 0; e < 8; ++e) {
      int k = ks * 32 + ((lane >> 4) << 3) + e;
      int d = nt * 16 + (lane & 15);
      bw2[(size_t)t * 8 + e] = (short)to_bf16u(mw2[k * D + d]);
    }
    return;
  }
  const int row0 = blockIdx.x * 8;
  __shared__ float xs[8][128];
  __shared__ float part[2][8][256];   // team-1 partials (ai, aj)

  {
    const int r = tid >> 6;           // 0..7, wave = row
    const int c2 = (tid & 63) << 1;
    float2 v = *(const float2*)(nodes + (size_t)(row0 + r) * D + c2);
    float s1 = v.x + v.y;
    float s2 = v.x * v.x + v.y * v.y;
#pragma unroll
    for (int off = 1; off < 64; off <<= 1) {
      s1 += __shfl_xor(s1, off);
      s2 += __shfl_xor(s2, off);
    }
    float mu = s1 * (1.0f / 128.0f);
    float var = s2 * (1.0f / 128.0f) - mu * mu;
    float rsig = rsqrtf(var + 1e-5f);
    float m = node_mask[row0 + r];
    float2 g2 = *(const float2*)(ln_g + c2);
    float2 b2 = *(const float2*)(ln_b + c2);
    xs[r][c2]     = ((v.x - mu) * rsig * g2.x + b2.x) * m;
    xs[r][c2 + 1] = ((v.y - mu) * rsig * g2.y + b2.y) * m;
  }
  __syncthreads();

  const int col = tid & 255, team = tid >> 8, d0 = team * 64;
  float ai[8], aj[8];
#pragma unroll
  for (int rr = 0; rr < 8; ++rr) { ai[rr] = 0.f; aj[rr] = 0.f; }
#pragma unroll 4
  for (int d = d0; d < d0 + 64; ++d) {
    float wi = mw1[d * H + col];
    float wj = mw1[(D + d) * H + col];
#pragma unroll
    for (int rr = 0; rr < 8; ++rr) {
      float xv = xs[rr][d];
      ai[rr] = fmaf(xv, wi, ai[rr]);
      aj[rr] = fmaf(xv, wj, aj[rr]);
    }
  }
  if (team == 1) {
#pragma unroll
    for (int rr = 0; rr < 8; ++rr) {
      part[0][rr][col] = ai[rr];
      part[1][rr][col] = aj[rr];
    }
  }
  __syncthreads();
  if (team == 0) {
#pragma unroll
    for (int rr = 0; rr < 8; ++rr) {
      float a = ai[rr] + part[0][rr][col];
      float c = aj[rr] + part[1][rr][col];
      xi_p[(size_t)(row0 + rr) * H + col] = a;
      xjb[(size_t)(row0 + rr) * H + col] = to_bf16u(c);
    }
  }
}

// ---------------- Kernel 2: msgs GEMM + mask + sum over j -> agg ----------------
// R8-proven tile (TM=32, NT=128, mf=2, acc[2][8]=64 AGPR, B staged in LDS, full
// unroll). ONE change vs R8: per-wave ks-phase ROTATION — ks = (kk + w) & 7.
// R8's pipes were near-serialized (Mfma 14.2us + VALU 25.6us + LDS ~18us ~ dur):
// all 8 waves left the staging barrier in lockstep running identical streams.
// Rotation puts the 8 waves at 8 different loop phases so one wave's MFMA burst
// overlaps another's A-build VALU and a third's ds_reads (m114 co-issue).
// Costs nothing: no extra regs, no extra traffic; fp-sum reorder only.
// (R12 lesson: B-from-global = 1.07GB L2 = +24us. Keep LDS staging.)
__global__ __launch_bounds__(512, 4) void k_msgs(
    const float* __restrict__ xi_p, const unsigned short* __restrict__ xjb,
    const short* __restrict__ bw2g, const float* __restrict__ mb1,
    const float* __restrict__ mb2, const float* __restrict__ node_mask,
    float* __restrict__ agg) {
  const int b = blockIdx.y;
  const int i0 = blockIdx.x * 2;
  const int tid = threadIdx.x;           // 0..511
  const int w = tid >> 6, l = tid & 63;  // 8 waves
  const int iw = w >> 2;                 // 0..1: which i
  const int jbase = (w & 3) * 32;        // which 32-row j-slab
  const int lg = l >> 4, l15 = l & 15;

  __shared__ short bw2s[32768];          // 64 KB B fragments
  __shared__ float cs[2][256];           // xi_p row + mb1 (f32), per i
  __shared__ float mb2s[128], maskS[128];
  __shared__ float waveAgg[8][128];

  {
    const uint4v* src = (const uint4v*)bw2g;
    uint4v* dst = (uint4v*)bw2s;
#pragma unroll
    for (int c = 0; c < 8; ++c) dst[c * 512 + tid] = src[c * 512 + tid];
  }
  {
    int ii = tid >> 8, k = tid & 255;    // 512 threads = 2 x 256
    cs[ii][k] = xi_p[(size_t)(b * NN + i0 + ii) * H + k] + mb1[k];
  }
  if (tid < 128) { mb2s[tid] = mb2[tid]; maskS[tid] = node_mask[b * NN + tid]; }
  __syncthreads();

  const unsigned short* xrow[2];
#pragma unroll
  for (int mf = 0; mf < 2; ++mf)
    xrow[mf] = xjb + (size_t)(b * NN + jbase + mf * 16 + l15) * H;

  f32x4 acc[2][8];
#pragma unroll
  for (int mf = 0; mf < 2; ++mf)
#pragma unroll
    for (int nt = 0; nt < 8; ++nt)
      acc[mf][nt] = (f32x4){0.f, 0.f, 0.f, 0.f};

  const short8* bfrag = (const short8*)bw2s;

#pragma unroll
  for (int kk = 0; kk < 8; ++kk) {
    const int ks = (kk + w) & 7;         // per-wave phase rotation
    const int kb = ks * 32 + lg * 8;     // bf16-elem k offset
    f32x2 cc[4];
    {
      f32x4 c0 = *(const f32x4*)(&cs[iw][kb]);
      f32x4 c1 = *(const f32x4*)(&cs[iw][kb + 4]);
      cc[0] = (f32x2){c0.x, c0.y}; cc[1] = (f32x2){c0.z, c0.w};
      cc[2] = (f32x2){c1.x, c1.y}; cc[3] = (f32x2){c1.z, c1.w};
    }
    short8 af[2];
#pragma unroll
    for (int mf = 0; mf < 2; ++mf) {
      uint4v xu = *(const uint4v*)(xrow[mf] + kb);
      uint4v au;
#pragma unroll
      for (int p = 0; p < 4; ++p) {
        f32x2 xf;
        xf[0] = __builtin_bit_cast(float, xu[p] << 16);
        xf[1] = __builtin_bit_cast(float, xu[p] & 0xffff0000u);
        f32x2 s = pk_add(xf, cc[p]);
        au[p] = pk_relu(cvt_pk(s[0], s[1]));
      }
      af[mf] = __builtin_bit_cast(short8, au);
    }
#pragma unroll
    for (int nt = 0; nt < 8; ++nt) {
      short8 bf = bfrag[(ks * 8 + nt) * 64 + l];
#pragma unroll
      for (int mf = 0; mf < 2; ++mf)
        acc[mf][nt] = __builtin_amdgcn_mfma_f32_16x16x32_bf16(af[mf], bf, acc[mf][nt], 0, 0, 0);
    }
  }

  // Epilogue: relu(acc+mb2)*mask_j, column-sum over the wave's 32 rows.
#pragma unroll
  for (int nt = 0; nt < 8; ++nt) {
    const float bias = mb2s[nt * 16 + l15];
    float s = 0.f;
#pragma unroll
    for (int mf = 0; mf < 2; ++mf) {
      const int jb = jbase + mf * 16 + lg * 4;
#pragma unroll
      for (int r = 0; r < 4; ++r)
        s = fmaf(fmaxf(acc[mf][nt][r] + bias, 0.f), maskS[jb + r], s);
    }
    s += __shfl_xor(s, 16);
    s += __shfl_xor(s, 32);
    if (l < 16) waveAgg[w][nt * 16 + l15] = s;
  }
  __syncthreads();
  if (tid < 256) {
    const int ii = tid >> 7, col = tid & 127;  // 2 i's x 128 cols
    agg[(size_t)(b * NN + i0 + ii) * D + col] =
        waveAgg[ii * 4][col] + waveAgg[ii * 4 + 1][col] +
        waveAgg[ii * 4 + 2][col] + waveAgg[ii * 4 + 3][col];
  }
}

// ---------------- Kernel 3: update MLP + residual + mask ----------------
__global__ __launch_bounds__(512) void k_upd(
    const float* __restrict__ nodes, const float* __restrict__ agg,
    const float* __restrict__ uw1, const float* __restrict__ ub1,
    const float* __restrict__ uw2, const float* __restrict__ ub2,
    const float* __restrict__ node_mask, float* __restrict__ out) {
  const int row0 = blockIdx.x * 8;
  const int tid = threadIdx.x;
  __shared__ float ns[8][128];
  __shared__ float as2[8][128];
  __shared__ float us[8][256];
  __shared__ float pus[8][256];
  {
    const int r = tid >> 6;
    const int c2 = (tid & 63) << 1;
    *(float2*)(&ns[r][c2]) = *(const float2*)(nodes + (size_t)(row0 + r) * D + c2);
    *(float2*)(&as2[r][c2]) = *(const float2*)(agg + (size_t)(row0 + r) * D + c2);
  }
  __syncthreads();

  const int col = tid & 255, team = tid >> 8, d0 = team * 64;
  float acc8[8];
#pragma unroll
  for (int rr = 0; rr < 8; ++rr) acc8[rr] = 0.f;
#pragma unroll 4
  for (int d = d0; d < d0 + 64; ++d) {
    float wa = uw1[d * H + col];
    float wb = uw1[(D + d) * H + col];
#pragma unroll
    for (int rr = 0; rr < 8; ++rr) {
      acc8[rr] = fmaf(ns[rr][d], wa, acc8[rr]);
      acc8[rr] = fmaf(as2[rr][d], wb, acc8[rr]);
    }
  }
  if (team == 1) {
#pragma unroll
    for (int rr = 0; rr < 8; ++rr) pus[rr][col] = acc8[rr];
  }
  __syncthreads();
  if (team == 0) {
    float bias = ub1[col];
#pragma unroll
    for (int rr = 0; rr < 8; ++rr)
      us[rr][col] = fmaxf(acc8[rr] + pus[rr][col] + bias, 0.f);
  }
  __syncthreads();

  const int colD = tid & 127, rg = tid >> 7;  // rows rg and rg+4
  float o0 = 0.f, o1 = 0.f;
#pragma unroll 8
  for (int h = 0; h < 256; ++h) {
    float wv = uw2[h * D + colD];
    o0 = fmaf(us[rg][h], wv, o0);
    o1 = fmaf(us[rg + 4][h], wv, o1);
  }
  const float ub2v = ub2[colD];
  out[(size_t)(row0 + rg) * D + colD] =
      (ns[rg][colD] + o0 + ub2v) * node_mask[row0 + rg];
  out[(size_t)(row0 + rg + 4) * D + colD] =
      (ns[rg + 4][colD] + o1 + ub2v) * node_mask[row0 + rg + 4];
}

extern "C" void kernel_launch(void* const* d_in, const int* in_sizes, int n_in,
                              void* d_out, int out_size, void* d_ws, size_t ws_size,
                              hipStream_t stream) {
  (void)in_sizes; (void)n_in; (void)out_size; (void)ws_size;
  const float* nodes     = (const float*)d_in[0];
  const float* node_mask = (const float*)d_in[1];
  const float* ln_g      = (const float*)d_in[2];
  const float* ln_b      = (const float*)d_in[3];
  const float* mw1       = (const float*)d_in[4];
  const float* mb1       = (const float*)d_in[5];
  const float* mw2       = (const float*)d_in[6];
  const float* mb2       = (const float*)d_in[7];
  const float* uw1       = (const float*)d_in[8];
  const float* ub1       = (const float*)d_in[9];
  const float* uw2       = (const float*)d_in[10];
  const float* ub2       = (const float*)d_in[11];
  float* out = (float*)d_out;

  char* ws = (char*)d_ws;
  float*          xi_p = (float*)(ws);                              // 4 MB
  unsigned short* xjb  = (unsigned short*)(ws + ((size_t)4 << 20)); // 2 MB
  float*          agg  = (float*)(ws + ((size_t)6 << 20));          // 2 MB
  short*          bw2  = (short*)(ws + ((size_t)8 << 20));          // 64 KB

  k_ln_proj<<<520, 512, 0, stream>>>(nodes, node_mask, ln_g, ln_b, mw1, mw2,
                                     xi_p, xjb, bw2);
  k_msgs<<<dim3(NN / 2, NB), 512, 0, stream>>>(xi_p, xjb, bw2, mb1, mb2, node_mask, agg);
  k_upd<<<512, 512, 0, stream>>>(nodes, agg, uw1, ub1, uw2, ub2, node_mask, out);
}